// Round 4
// baseline (151.985 us; speedup 1.0000x reference)
//
#include <hip/hip_runtime.h>
#include <cstdint>
#include <cstddef>

#define EPSV 1e-5f
typedef uint32_t u32;

// ---------------- stage A: conv1x1(q,k) + BN + ReLU + spatial partial-sum ----------------
// grid: 512 blocks = 128 n x 4 px-groups (256 px each; group 3 is the 16-px tail).
// 256 threads = 4 o-groups (16 outputs each) x 64 px-lanes (float4 of pixels each).
// Register-tiled: per c-iter/thread: 1 float4 x-load + 16 W floats (LDS broadcast) + 64 FMA.
// Each wave owns a disjoint o-range -> wave-local shuffle reduction only.
__global__ __launch_bounds__(256) void k_stageA(
    const float* __restrict__ x,
    const float* __restrict__ wq, const float* __restrict__ bq, const float* __restrict__ gq,
    const float* __restrict__ betaq, const float* __restrict__ mq, const float* __restrict__ vq,
    const float* __restrict__ wk, const float* __restrict__ bk, const float* __restrict__ gk,
    const float* __restrict__ betak, const float* __restrict__ mk, const float* __restrict__ vk,
    float* __restrict__ qk_part)
{
  __shared__ float Wsh[256][64];  // 64 KiB, scale-folded, Wsh[c][o]
  __shared__ float Dsh[64];       // (b-m)*s+beta per o

  const int tid = threadIdx.x;
  const int n  = blockIdx.x >> 2;
  const int g  = blockIdx.x & 3;
  const int og = tid >> 6;        // o in [og*16, og*16+16)
  const int pl = tid & 63;
  const int P0 = g*256 + pl*4;    // 4 contiguous pixels; 784%4==0 -> all-or-nothing valid
  const bool pvalid = (P0 < 784);

  for (int i = tid; i < 256*64; i += 256) {
    const int o = i & 63, c = i >> 6;
    float w, gg, v;
    if (o < 32) { w = wq[o*256 + c];      gg = gq[o];    v = vq[o]; }
    else        { w = wk[(o-32)*256 + c]; gg = gk[o-32]; v = vk[o-32]; }
    Wsh[c][o] = w * (gg * rsqrtf(v + EPSV));
  }
  if (tid < 64) {
    const int o = tid;
    float gg,b,be,m,v;
    if (o < 32) { gg=gq[o];    b=bq[o];    be=betaq[o];    m=mq[o];    v=vq[o]; }
    else        { gg=gk[o-32]; b=bk[o-32]; be=betak[o-32]; m=mk[o-32]; v=vk[o-32]; }
    const float s = gg * rsqrtf(v + EPSV);
    Dsh[o] = (b - m)*s + be;
  }
  __syncthreads();

  float acc[4][16];
#pragma unroll
  for (int j = 0; j < 4; ++j)
#pragma unroll
    for (int o = 0; o < 16; ++o) acc[j][o] = 0.f;

  if (pvalid) {
    const float4* xp4 = reinterpret_cast<const float4*>(x + (size_t)n*200704) + (P0 >> 2);
    float4 xv = xp4[0];
    for (int c = 0; c < 256; ++c) {
      float4 xn = make_float4(0.f,0.f,0.f,0.f);
      if (c < 255) xn = xp4[(size_t)(c+1)*196];       // prefetch next channel
      float w[16];
#pragma unroll
      for (int o = 0; o < 16; ++o) w[o] = Wsh[c][og*16 + o];
#pragma unroll
      for (int o = 0; o < 16; ++o) {
        acc[0][o] = fmaf(xv.x, w[o], acc[0][o]);
        acc[1][o] = fmaf(xv.y, w[o], acc[1][o]);
        acc[2][o] = fmaf(xv.z, w[o], acc[2][o]);
        acc[3][o] = fmaf(xv.w, w[o], acc[3][o]);
      }
      xv = xn;
    }
    // per-pixel BN + ReLU epilogue (all 4 px valid when pvalid)
#pragma unroll
    for (int o = 0; o < 16; ++o) {
      const float d = Dsh[og*16 + o];
#pragma unroll
      for (int j = 0; j < 4; ++j) acc[j][o] = fmaxf(acc[j][o] + d, 0.f);
    }
  }

  // sum 4 px within thread, then wave-local shuffle reduce (invalid lanes hold 0)
  float s16[16];
#pragma unroll
  for (int o = 0; o < 16; ++o)
    s16[o] = (acc[0][o] + acc[1][o]) + (acc[2][o] + acc[3][o]);
#pragma unroll
  for (int o = 0; o < 16; ++o) {
    float v = s16[o];
    v += __shfl_down(v, 32, 64);
    v += __shfl_down(v, 16, 64);
    v += __shfl_down(v, 8, 64);
    v += __shfl_down(v, 4, 64);
    v += __shfl_down(v, 2, 64);
    v += __shfl_down(v, 1, 64);
    s16[o] = v;
  }
  if (pl == 0) {
#pragma unroll
    for (int o = 0; o < 16; ++o)
      qk_part[(size_t)blockIdx.x*64 + og*16 + o] = s16[o];
  }
}

// ---------------- stage B: per-group 8x8 attention + conv_inflate + BN + ReLU + sigmoid ----------------
__global__ __launch_bounds__(256) void k_stageB(
    const float* __restrict__ qk_part,
    const float* __restrict__ wi, const float* __restrict__ bi, const float* __restrict__ gi,
    const float* __restrict__ betai, const float* __restrict__ mi, const float* __restrict__ vi,
    float* __restrict__ gate)
{
  __shared__ float ql[8][32], vl[8][32], attl[8][8], qul[8][32];
  const int tid = threadIdx.x;
  const int b = blockIdx.x;

  { // gather the 4 px-group sums, convert to means
    const int i = tid >> 5, c = tid & 31;
    const int n = b*8 + i;
    float sq = 0.f, sv = 0.f;
#pragma unroll
    for (int qq = 0; qq < 4; ++qq) {
      sq += qk_part[(size_t)(n*4 + qq)*64 + c];
      sv += qk_part[(size_t)(n*4 + qq)*64 + 32 + c];
    }
    ql[i][c] = sq * (1.f/784.f);
    vl[i][c] = sv * (1.f/784.f);
  }
  __syncthreads();

  if (tid < 64) { // att[i][j] = -q_i.q_j ; softmax over i (axis 1) for fixed j
    const int i = tid >> 3, j = tid & 7;
    float d = 0.f;
#pragma unroll
    for (int c = 0; c < 32; ++c) d += ql[i][c]*ql[j][c];
    float a = -d;
    float m = a;                        // reduce over i: tid bits 3..5
    m = fmaxf(m, __shfl_xor(m, 8, 64));
    m = fmaxf(m, __shfl_xor(m, 16, 64));
    m = fmaxf(m, __shfl_xor(m, 32, 64));
    const float e = __expf(a - m);
    float s = e;
    s += __shfl_xor(s, 8, 64);
    s += __shfl_xor(s, 16, 64);
    s += __shfl_xor(s, 32, 64);
    attl[i][j] = e / s;
  }
  __syncthreads();

  { // q_upd[i][c] = sum_j att[i][j]*v[j][c] + v[i][c]
    const int i = tid >> 5, c = tid & 31;
    float acc = vl[i][c];
#pragma unroll
    for (int j = 0; j < 8; ++j) acc = fmaf(attl[i][j], vl[j][c], acc);
    qul[i][c] = acc;
  }
  __syncthreads();

  { // y[n,cout] = q_upd . wi[cout,:] (+bi), BN, ReLU, sigmoid
    const int cout = tid;
    float w[32];
#pragma unroll
    for (int k = 0; k < 32; ++k) w[k] = wi[cout*32 + k];
    const float s  = gi[cout] * rsqrtf(vi[cout] + EPSV);
    const float dd = (bi[cout] - mi[cout]) * s + betai[cout];
#pragma unroll
    for (int i = 0; i < 8; ++i) {
      float y = 0.f;
#pragma unroll
      for (int k = 0; k < 32; ++k) y = fmaf(qul[i][k], w[k], y);
      const float t = fmaxf(fmaf(y, s, dd), 0.f);
      gate[(size_t)(b*8 + i)*256 + cout] = 1.f / (1.f + __expf(-t));
    }
  }
}

// ---------------- stage C: out = gate[n,c] * x ----------------
__global__ __launch_bounds__(256) void k_gateMul(
    const float* __restrict__ x, const float* __restrict__ gate, float* __restrict__ out)
{
  const u32 nchunk = 128u*256u*196u;   // 6,422,528 float4 chunks
  const u32 stride = gridDim.x * 256u;
  for (u32 q = blockIdx.x*256u + threadIdx.x; q < nchunk; q += stride) {
    const u32 cn = q / 196u;           // n*256 + c
    const float g = gate[cn];
    const float4 v = reinterpret_cast<const float4*>(x)[q];
    float4 o4;
    o4.x = v.x * g; o4.y = v.y * g; o4.z = v.z * g; o4.w = v.w * g;
    reinterpret_cast<float4*>(out)[q] = o4;
  }
}

extern "C" void kernel_launch(void* const* d_in, const int* in_sizes, int n_in,
                              void* d_out, int out_size, void* d_ws, size_t ws_size,
                              hipStream_t stream) {
  const float* x    = (const float*)d_in[0];
  const float* wq   = (const float*)d_in[1];
  const float* bq   = (const float*)d_in[2];
  const float* gq   = (const float*)d_in[3];
  const float* betaq= (const float*)d_in[4];
  const float* mq   = (const float*)d_in[5];
  const float* vq   = (const float*)d_in[6];
  const float* wk   = (const float*)d_in[7];
  const float* bk   = (const float*)d_in[8];
  const float* gk   = (const float*)d_in[9];
  const float* betak= (const float*)d_in[10];
  const float* mk   = (const float*)d_in[11];
  const float* vk   = (const float*)d_in[12];
  const float* wi   = (const float*)d_in[13];
  const float* bi   = (const float*)d_in[14];
  const float* gi   = (const float*)d_in[15];
  const float* betai= (const float*)d_in[16];
  const float* mi   = (const float*)d_in[17];
  const float* vi   = (const float*)d_in[18];

  float* qk_part = (float*)d_ws;                                            // 512*64 f32 = 128KB
  float* gate    = (float*)((char*)d_ws + (size_t)512*64*sizeof(float));    // 128*256 f32 = 128KB

  k_stageA<<<512, 256, 0, stream>>>(x, wq,bq,gq,betaq,mq,vq, wk,bk,gk,betak,mk,vk, qk_part);
  k_stageB<<<16, 256, 0, stream>>>(qk_part, wi,bi,gi,betai,mi,vi, gate);
  k_gateMul<<<2048, 256, 0, stream>>>(x, gate, (float*)d_out);
}

// Round 5
// 104.040 us; speedup vs baseline: 1.4608x; 1.4608x over previous
//
#include <hip/hip_runtime.h>
#include <cstdint>
#include <cstddef>

#define EPSV 1e-5f
typedef uint32_t u32;

// ---------------- prep: fold BN scale into W, transpose to Wt[c][64]; epilogue consts D[64] ----------
__global__ __launch_bounds__(256) void k_prep(
    const float* __restrict__ wq, const float* __restrict__ bq, const float* __restrict__ gq,
    const float* __restrict__ betaq, const float* __restrict__ mq, const float* __restrict__ vq,
    const float* __restrict__ wk, const float* __restrict__ bk, const float* __restrict__ gk,
    const float* __restrict__ betak, const float* __restrict__ mk, const float* __restrict__ vk,
    float* __restrict__ Wt, float* __restrict__ D)
{
  const int idx = blockIdx.x*256 + threadIdx.x;     // 64 blocks x 256 = 16384 = 256c x 64o
  const int o = idx & 63, c = idx >> 6;
  float w, g, v;
  if (o < 32) { w = wq[o*256 + c];      g = gq[o];    v = vq[o]; }
  else        { w = wk[(o-32)*256 + c]; g = gk[o-32]; v = vk[o-32]; }
  Wt[c*64 + o] = w * (g * rsqrtf(v + EPSV));
  if (idx < 64) {
    float gg,b,be,m,vv;
    if (idx < 32) { gg=gq[idx];    b=bq[idx];    be=betaq[idx];    m=mq[idx];    vv=vq[idx]; }
    else          { gg=gk[idx-32]; b=bk[idx-32]; be=betak[idx-32]; m=mk[idx-32]; vv=vk[idx-32]; }
    const float s = gg * rsqrtf(vv + EPSV);
    D[idx] = (b - m)*s + be;
  }
}

// ---------------- stage A: conv1x1(q,k) + BN + ReLU + spatial partial-sum ----------------
// grid: 512 blocks = 128 n x 4 chunk-groups. 256 threads = 4 o-groups x 64 px-lanes.
// No LDS. W-row is wave-uniform (readfirstlane base -> scalar loads). x prefetch 2 deep.
// Branchless main loop: clamped addresses, invalid lanes zeroed in epilogue.
__global__ __launch_bounds__(256) void k_stageA(
    const float* __restrict__ x, const float* __restrict__ Wt, const float* __restrict__ D,
    float* __restrict__ qk_part)
{
  const int tid = threadIdx.x;
  const int n = blockIdx.x >> 2, g = blockIdx.x & 3;
  const int og4 = __builtin_amdgcn_readfirstlane((tid >> 6) << 4);  // 0,16,32,48 (SGPR)
  const int pl = tid & 63;
  const int C0 = g*64 + pl;                   // float4-chunk id within the image (196 real)
  const bool pvalid = (C0 < 196);
  const int C0c = pvalid ? C0 : 195;          // clamp -> loads always legal, wave-converged
  const float4* xp4 = reinterpret_cast<const float4*>(x + (size_t)n*200704) + C0c;
  const float* wt = Wt + og4;                 // wave-uniform base

  float acc[4][16];
#pragma unroll
  for (int j = 0; j < 4; ++j)
#pragma unroll
    for (int o = 0; o < 16; ++o) acc[j][o] = 0.f;

  float4 xa = xp4[0];
  float4 xb = xp4[196];
#pragma unroll 2
  for (int c = 0; c < 256; ++c) {
    const int cn = (c + 2 < 256) ? (c + 2) : 255;          // clamped prefetch (branchless)
    const float4 xn = xp4[(size_t)cn*196];
    float w[16];
#pragma unroll
    for (int o = 0; o < 16; ++o) w[o] = wt[c*64 + o];      // uniform 64B row
#pragma unroll
    for (int o = 0; o < 16; ++o) {
      acc[0][o] = fmaf(xa.x, w[o], acc[0][o]);
      acc[1][o] = fmaf(xa.y, w[o], acc[1][o]);
      acc[2][o] = fmaf(xa.z, w[o], acc[2][o]);
      acc[3][o] = fmaf(xa.w, w[o], acc[3][o]);
    }
    xa = xb; xb = xn;
  }

  // epilogue: BN shift + ReLU for valid lanes, zero for clamped lanes; sum 4 px in-thread
  float s16[16];
#pragma unroll
  for (int o = 0; o < 16; ++o) {
    const float d = D[og4 + o];
    const float p0 = fmaxf(acc[0][o] + d, 0.f);
    const float p1 = fmaxf(acc[1][o] + d, 0.f);
    const float p2 = fmaxf(acc[2][o] + d, 0.f);
    const float p3 = fmaxf(acc[3][o] + d, 0.f);
    s16[o] = pvalid ? ((p0 + p1) + (p2 + p3)) : 0.f;
  }
#pragma unroll
  for (int o = 0; o < 16; ++o) {
    float v = s16[o];
    v += __shfl_down(v, 32, 64);
    v += __shfl_down(v, 16, 64);
    v += __shfl_down(v, 8, 64);
    v += __shfl_down(v, 4, 64);
    v += __shfl_down(v, 2, 64);
    v += __shfl_down(v, 1, 64);
    s16[o] = v;
  }
  if (pl == 0) {
#pragma unroll
    for (int o = 0; o < 16; ++o)
      qk_part[(size_t)blockIdx.x*64 + og4 + o] = s16[o];
  }
}

// ---------------- stage B: per-group 8x8 attention + conv_inflate + BN + ReLU + sigmoid ----------------
__global__ __launch_bounds__(256) void k_stageB(
    const float* __restrict__ qk_part,
    const float* __restrict__ wi, const float* __restrict__ bi, const float* __restrict__ gi,
    const float* __restrict__ betai, const float* __restrict__ mi, const float* __restrict__ vi,
    float* __restrict__ gate)
{
  __shared__ float ql[8][32], vl[8][32], attl[8][8], qul[8][32];
  const int tid = threadIdx.x;
  const int b = blockIdx.x;

  { // gather the 4 chunk-group sums, convert to means
    const int i = tid >> 5, c = tid & 31;
    const int n = b*8 + i;
    float sq = 0.f, sv = 0.f;
#pragma unroll
    for (int qq = 0; qq < 4; ++qq) {
      sq += qk_part[(size_t)(n*4 + qq)*64 + c];
      sv += qk_part[(size_t)(n*4 + qq)*64 + 32 + c];
    }
    ql[i][c] = sq * (1.f/784.f);
    vl[i][c] = sv * (1.f/784.f);
  }
  __syncthreads();

  if (tid < 64) { // att[i][j] = -q_i.q_j ; softmax over i (axis 1) for fixed j
    const int i = tid >> 3, j = tid & 7;
    float d = 0.f;
#pragma unroll
    for (int c = 0; c < 32; ++c) d += ql[i][c]*ql[j][c];
    float a = -d;
    float m = a;                        // reduce over i: tid bits 3..5
    m = fmaxf(m, __shfl_xor(m, 8, 64));
    m = fmaxf(m, __shfl_xor(m, 16, 64));
    m = fmaxf(m, __shfl_xor(m, 32, 64));
    const float e = __expf(a - m);
    float s = e;
    s += __shfl_xor(s, 8, 64);
    s += __shfl_xor(s, 16, 64);
    s += __shfl_xor(s, 32, 64);
    attl[i][j] = e / s;
  }
  __syncthreads();

  { // q_upd[i][c] = sum_j att[i][j]*v[j][c] + v[i][c]
    const int i = tid >> 5, c = tid & 31;
    float acc = vl[i][c];
#pragma unroll
    for (int j = 0; j < 8; ++j) acc = fmaf(attl[i][j], vl[j][c], acc);
    qul[i][c] = acc;
  }
  __syncthreads();

  { // y[n,cout] = q_upd . wi[cout,:] (+bi), BN, ReLU, sigmoid
    const int cout = tid;
    float w[32];
#pragma unroll
    for (int k = 0; k < 32; ++k) w[k] = wi[cout*32 + k];
    const float s  = gi[cout] * rsqrtf(vi[cout] + EPSV);
    const float dd = (bi[cout] - mi[cout]) * s + betai[cout];
#pragma unroll
    for (int i = 0; i < 8; ++i) {
      float y = 0.f;
#pragma unroll
      for (int k = 0; k < 32; ++k) y = fmaf(qul[i][k], w[k], y);
      const float t = fmaxf(fmaf(y, s, dd), 0.f);
      gate[(size_t)(b*8 + i)*256 + cout] = 1.f / (1.f + __expf(-t));
    }
  }
}

// ---------------- stage C: out = gate[n,c] * x ----------------
__global__ __launch_bounds__(256) void k_gateMul(
    const float* __restrict__ x, const float* __restrict__ gate, float* __restrict__ out)
{
  const u32 nchunk = 128u*256u*196u;   // 6,422,528 float4 chunks
  const u32 stride = gridDim.x * 256u;
  for (u32 q = blockIdx.x*256u + threadIdx.x; q < nchunk; q += stride) {
    const u32 cn = q / 196u;           // n*256 + c
    const float g = gate[cn];
    const float4 v = reinterpret_cast<const float4*>(x)[q];
    float4 o4;
    o4.x = v.x * g; o4.y = v.y * g; o4.z = v.z * g; o4.w = v.w * g;
    reinterpret_cast<float4*>(out)[q] = o4;
  }
}

extern "C" void kernel_launch(void* const* d_in, const int* in_sizes, int n_in,
                              void* d_out, int out_size, void* d_ws, size_t ws_size,
                              hipStream_t stream) {
  const float* x    = (const float*)d_in[0];
  const float* wq   = (const float*)d_in[1];
  const float* bq   = (const float*)d_in[2];
  const float* gq   = (const float*)d_in[3];
  const float* betaq= (const float*)d_in[4];
  const float* mq   = (const float*)d_in[5];
  const float* vq   = (const float*)d_in[6];
  const float* wk   = (const float*)d_in[7];
  const float* bk   = (const float*)d_in[8];
  const float* gk   = (const float*)d_in[9];
  const float* betak= (const float*)d_in[10];
  const float* mk   = (const float*)d_in[11];
  const float* vk   = (const float*)d_in[12];
  const float* wi   = (const float*)d_in[13];
  const float* bi   = (const float*)d_in[14];
  const float* gi   = (const float*)d_in[15];
  const float* betai= (const float*)d_in[16];
  const float* mi   = (const float*)d_in[17];
  const float* vi   = (const float*)d_in[18];

  char* ws = (char*)d_ws;
  float* qk_part = (float*)(ws);                     // 512*64*4   = 131072 B
  float* gate    = (float*)(ws + 131072);            // 128*256*4  = 131072 B
  float* Wt      = (float*)(ws + 262144);            // 256*64*4   =  65536 B
  float* Dc      = (float*)(ws + 327680);            // 64*4

  k_prep<<<64, 256, 0, stream>>>(wq,bq,gq,betaq,mq,vq, wk,bk,gk,betak,mk,vk, Wt, Dc);
  k_stageA<<<512, 256, 0, stream>>>(x, Wt, Dc, qk_part);
  k_stageB<<<16, 256, 0, stream>>>(qk_part, wi,bi,gi,betai,mi,vi, gate);
  k_gateMul<<<2048, 256, 0, stream>>>(x, gate, (float*)d_out);
}